// Round 9
// baseline (1809.762 us; speedup 1.0000x reference)
//
#include <hip/hip_runtime.h>
#include <hip/hip_cooperative_groups.h>
#include <math.h>

namespace cg = cooperative_groups;

#define N_NODES 50000
#define E_EDGES 1600000
#define F_IN    2000
#define D       20
#define NCOL    160   // 2 edge types * [q s k v] * 20
#define KPAD    2016  // 63 * 32
#define NBNP    64    // BN partial slots

#define INV_SQRT_D 0.22360679774997896f

typedef __bf16 bf16x8 __attribute__((ext_vector_type(8)));
typedef __bf16 bf16x4 __attribute__((ext_vector_type(4)));
typedef float  f32x4  __attribute__((ext_vector_type(4)));

// ---------------- pack weights + zero accumulators --------------------------------------
__global__ void pack_kernel(
    const float* __restrict__ W0q, const float* __restrict__ W0k,
    const float* __restrict__ W0v, const float* __restrict__ W0s,
    const float* __restrict__ b0q, const float* __restrict__ b0k,
    const float* __restrict__ b0v, const float* __restrict__ b0s,
    const float* __restrict__ Wq,  const float* __restrict__ Wk,
    const float* __restrict__ Wv,  const float* __restrict__ Ws_,
    const float* __restrict__ bq,  const float* __restrict__ bk,
    const float* __restrict__ bv,  const float* __restrict__ bs_,
    __bf16* __restrict__ B0, float* __restrict__ bias0,
    float* __restrict__ WL, float* __restrict__ biasL,
    float* __restrict__ bnp, int* __restrict__ deg)
{
  long idx = (long)blockIdx.x * blockDim.x + threadIdx.x;
  if (idx < (long)NCOL*KPAD) {              // B0T: [160][2016] bf16
    int col = (int)(idx / KPAD), k = (int)(idx % KPAD);
    int et = col / 80, r = col % 80, mat = r / 20, d = r % 20;
    const float* w = (mat==0)?W0q:(mat==1)?W0s:(mat==2)?W0k:W0v;
    float v = (k < F_IN) ? w[((size_t)et*F_IN + k)*D + d] : 0.f;
    B0[idx] = (__bf16)v;
    return;
  }
  idx -= (long)NCOL*KPAD;
  if (idx < 160) {                          // bias0
    int col = (int)idx;
    int et = col / 80, r = col % 80, mat = r / 20, d = r % 20;
    const float* b = (mat==0)?b0q:(mat==1)?b0s:(mat==2)?b0k:b0v;
    bias0[col] = b[et*D + d];
    return;
  }
  idx -= 160;
  if (idx < 9600) {                         // WL: 3 x [20][160]
    int l = (int)(idx / 3200), rem = (int)(idx % 3200);
    int k = rem / NCOL, col = rem % NCOL;
    int et = col / 80, r = col % 80, mat = r / 20, d = r % 20;
    const float* w = (mat==0)?Wq:(mat==1)?Ws_:(mat==2)?Wk:Wv;
    WL[idx] = w[(((size_t)l*2 + et)*D + k)*D + d];
    return;
  }
  idx -= 9600;
  if (idx < 480) {                          // biasL: 3 x [160]
    int l = (int)(idx / NCOL), col = (int)(idx % NCOL);
    int et = col / 80, r = col % 80, mat = r / 20, d = r % 20;
    const float* b = (mat==0)?bq:(mat==1)?bs_:(mat==2)?bk:bv;
    biasL[idx] = b[(l*2 + et)*D + d];
    return;
  }
  idx -= 480;
  if (idx < 4*NBNP*40) { bnp[idx] = 0.f; return; } // BN partials: [4][64][40]
  idx -= 4*NBNP*40;
  if (idx < 2*N_NODES) { deg[idx] = 0; return; }
}

// ---------------- CSR build (XCD-partitioned) --------------------------------------------
#define SC_EPT 16
#define SC_CHUNK (256*SC_EPT)

__global__ void hist_kernel(const int* __restrict__ same, const int* __restrict__ diff,
                            int* __restrict__ deg)
{
  const int part  = blockIdx.x & 7;
  const int chunk = blockIdx.x >> 3;
  const int lo = part * (N_NODES/8);
  const int hi = lo + (N_NODES/8);
  const long i0 = (long)chunk * SC_CHUNK + threadIdx.x;
#pragma unroll
  for (int it = 0; it < SC_EPT; ++it) {
    long i = i0 + (long)it*256;
    if (i >= 2L*E_EDGES) break;
    int et = (i >= E_EDGES) ? 1 : 0;
    long e = i - (long)et*E_EDGES;
    const int* ix = et ? diff : same;
    int dst = ix[E_EDGES + e];
    if (dst >= lo && dst < hi)
      atomicAdd(&deg[(size_t)et*N_NODES + dst], 1);
  }
}

__global__ void scan_kernel(const int* __restrict__ deg,
                            int* __restrict__ rowptr0, int* __restrict__ rowptr1,
                            int* __restrict__ next0, int* __restrict__ next1)
{
  const int et = blockIdx.x;
  const int* dg = deg + (size_t)et*N_NODES;
  int* rp = et ? rowptr1 : rowptr0;
  int* np = et ? next1 : next0;
  __shared__ int part[1024];
  const int t = threadIdx.x;
  const int per = (N_NODES + 1023) / 1024;  // 49
  const int b = t * per;
  const int e = (b + per < N_NODES) ? (b + per) : N_NODES;
  int s = 0;
  for (int i = b; i < e; i++) s += dg[i];
  part[t] = s;
  __syncthreads();
  for (int o = 1; o < 1024; o <<= 1) {
    int v = (t >= o) ? part[t-o] : 0;
    __syncthreads();
    part[t] += v;
    __syncthreads();
  }
  int run = (t == 0) ? 0 : part[t-1];
  for (int i = b; i < e; i++) {
    rp[i] = run; np[i] = run;
    run += dg[i];
  }
  if (t == 0) rp[N_NODES] = part[1023];
}

__global__ void scatter_kernel(const int* __restrict__ same, const int* __restrict__ diff,
                               int* __restrict__ next0, int* __restrict__ next1,
                               int* __restrict__ adj0, int* __restrict__ adj1)
{
  const int part  = blockIdx.x & 7;
  const int chunk = blockIdx.x >> 3;
  const int lo = part * (N_NODES/8);
  const int hi = lo + (N_NODES/8);
  const long i0 = (long)chunk * SC_CHUNK + threadIdx.x;
#pragma unroll
  for (int it = 0; it < SC_EPT; ++it) {
    long i = i0 + (long)it*256;
    if (i >= 2L*E_EDGES) break;
    int et = (i >= E_EDGES) ? 1 : 0;
    long e = i - (long)et*E_EDGES;
    const int* ix = et ? diff : same;
    int dst = ix[E_EDGES + e];
    if (dst >= lo && dst < hi) {
      int src = ix[e];
      int* np  = et ? next1 : next0;
      int* adj = et ? adj1  : adj0;
      int pos = atomicAdd(&np[dst], 1);
      adj[pos] = src;
    }
  }
}

// ---------------- cooperative mega kernel: gemm0 + 4x(proj, attn, BN) + final -----------
struct MegaP {
  const float* feat; const __bf16* B0; const float* bias0;
  const float* WL; const float* biasL;
  const float* w1; const float* w2; const float* gamma; const float* beta;
  const float* Wout; const float* bout;
  const int* rp0; const int* adj0; const int* rp1; const int* adj1;
  __bf16* QS; __bf16* KV0; __bf16* KV1;
  float* xpre4; float* bnp; float* out;
};

__launch_bounds__(256, 4)
__global__ void mega_kernel(MegaP P)
{
  cg::grid_group grid = cg::this_grid();
  __shared__ __align__(16) char smem[14336];
  const int t    = threadIdx.x;
  const int nblk = gridDim.x;
  const int lane = t & 63;
  const int wv   = t >> 6;

  // ============ phase G: layer-0 MFMA GEMM, grid-stride over 782 row-tiles ============
  {
    __bf16* as = (__bf16*)smem;         // 64*32 bf16 = 4KB
    const int wr   = wv >> 1;           // 0..1 -> rows wr*32
    const int wc   = wv & 1;            // 0..1 -> cols wc*80
    const int srow = t >> 2;            // staging row 0..63
    const int skc  = (t & 3) * 8;       // k chunk of 8
    const int lrow = lane & 15;
    const int lkb  = (lane >> 4) * 8;

    for (int tile = blockIdx.x; tile < 782; tile += nblk) {
      const int rb0  = tile * 64;
      const int arow = rb0 + srow;
      const float* aptr = P.feat + (size_t)arow * F_IN;

      f32x4 acc[2][5];
#pragma unroll
      for (int i = 0; i < 2; i++)
#pragma unroll
        for (int j = 0; j < 5; j++) acc[i][j] = (f32x4){0.f,0.f,0.f,0.f};

      float4 p0, p1;
      auto loadA = [&](int k0) {
        int k = k0 + skc;
        if (arow < N_NODES) {
          p0 = *(const float4*)(aptr + k);
          p1 = *(const float4*)(aptr + k + 4);
        } else {
          p0 = make_float4(0,0,0,0); p1 = p0;
        }
      };

      loadA(0);
      for (int s = 0; s < 63; s++) {
        bf16x8 h;
        h[0]=(__bf16)p0.x; h[1]=(__bf16)p0.y; h[2]=(__bf16)p0.z; h[3]=(__bf16)p0.w;
        h[4]=(__bf16)p1.x; h[5]=(__bf16)p1.y; h[6]=(__bf16)p1.z; h[7]=(__bf16)p1.w;
        __syncthreads();   // protect LDS WAR across iterations/tiles
        *(bf16x8*)&as[srow*32 + skc] = h;
        __syncthreads();
        if (s + 1 < 63) loadA((s + 1) * 32);

        bf16x8 af[2];
#pragma unroll
        for (int rf = 0; rf < 2; rf++)
          af[rf] = *(bf16x8*)&as[(wr*32 + rf*16 + lrow)*32 + lkb];
        bf16x8 bfr[5];
#pragma unroll
        for (int cf = 0; cf < 5; cf++)
          bfr[cf] = *(const bf16x8*)(P.B0 + (size_t)(wc*80 + cf*16 + lrow)*KPAD + s*32 + lkb);
#pragma unroll
        for (int rf = 0; rf < 2; rf++)
#pragma unroll
          for (int cf = 0; cf < 5; cf++)
            acc[rf][cf] = __builtin_amdgcn_mfma_f32_16x16x32_bf16(af[rf], bfr[cf], acc[rf][cf], 0, 0, 0);
      }

#pragma unroll
      for (int rf = 0; rf < 2; rf++) {
#pragma unroll
        for (int cf = 0; cf < 5; cf++) {
          int col = wc*80 + cf*16 + lrow;
          int et = col / 80, r = col % 80, mat = r / 20, d = r % 20;
          float bv = P.bias0[col];
          __bf16* kvp = et ? P.KV1 : P.KV0;
#pragma unroll
          for (int j = 0; j < 4; j++) {
            int row = rb0 + wr*32 + rf*16 + (lane >> 4)*4 + j;
            if (row < N_NODES) {
              __bf16 val = (__bf16)(acc[rf][cf][j] + bv);
              if (mat < 2) P.QS[(size_t)row*80 + et*40 + mat*20 + d] = val;
              else         kvp[(size_t)row*64 + (mat-2)*20 + d]     = val;
            }
          }
        }
      }
    }
  }
  grid.sync();

  // ============ layers: (proj for l>0) + attn + BN partials ============
  for (int l = 0; l < 4; ++l) {
    if (l > 0) {
      float* ws = (float*)smem;          // 3200
      float* xs = (float*)smem + 3200;   // 320
      float* Ac = (float*)smem + 3520;   // 20
      float* Bc = (float*)smem + 3540;   // 20
      const float* bnl  = P.bnp + (size_t)(l-1)*(NBNP*40);
      const float* W    = P.WL + (size_t)(l-1)*3200;
      const float* bias = P.biasL + (size_t)(l-1)*160;
      const float* xp   = P.xpre4 + (size_t)(l-1)*N_NODES*D;

      __syncthreads();
#pragma unroll
      for (int i = 0; i < 13; i++) {
        int idx = t + i*256;
        if (idx < 3200) ws[idx] = W[idx];
      }
      if (t < 20) {
        float s1 = 0.f, s2 = 0.f;
        for (int s = 0; s < NBNP; s++) { s1 += bnl[s*40 + t]; s2 += bnl[s*40 + 20 + t]; }
        float mu  = s1 * (1.f/N_NODES);
        float var = s2 * (1.f/N_NODES) - mu*mu;
        float a = rsqrtf(var + 1e-5f) * P.gamma[(l-1)*D + t];
        Ac[t] = a; Bc[t] = P.beta[(l-1)*D + t] - mu*a;
      }
      __syncthreads();

      for (int tile = blockIdx.x; tile < 3125; tile += nblk) {
        const int n0 = tile * 16;
        __syncthreads();   // xs WAR across tiles
#pragma unroll
        for (int i = 0; i < 2; i++) {
          int idx = t + i*256;
          if (idx < 320) {
            int nl = idx / 20, k = idx % 20;
            int n = n0 + nl;
            float x = (n < N_NODES) ? xp[(size_t)n*D + k] : 0.f;
            float y = x*Ac[k] + Bc[k];
            xs[idx] = (y > 0.f) ? y : 0.01f*y;
          }
        }
        __syncthreads();
#pragma unroll
        for (int i = 0; i < 10; i++) {
          int idx = t + i*256;
          int nl = idx / NCOL, col = idx % NCOL;
          int n = n0 + nl;
          if (n < N_NODES) {
            float acc = bias[col];
#pragma unroll
            for (int k = 0; k < 20; k++) acc += xs[nl*20 + k] * ws[k*NCOL + col];
            int et = col / 80, r = col % 80, mat = r / 20, d = r % 20;
            __bf16 val = (__bf16)acc;
            if (mat < 2) P.QS[(size_t)n*80 + et*40 + mat*20 + d] = val;
            else         (et ? P.KV1 : P.KV0)[(size_t)n*64 + (mat-2)*20 + d] = val;
          }
        }
      }
      grid.sync();
    }

    // ---- attn: one wave per node, lanes 0-31 et0 / 32-63 et1 ----
    {
      const int half = lane >> 5;
      const int sl   = lane & 31;
      const int* rowptr = half ? P.rp1 : P.rp0;
      const int* adj    = half ? P.adj1 : P.adj0;
      const __bf16* kvb = half ? P.KV1 : P.KV0;
      const float wa = P.w1[l], wb = P.w2[l];
      const float c0 = wa/(wa+wb), c1 = wb/(wa+wb);
      const float cme = half ? c1 : c0;
      const float cot = half ? c0 : c1;
      float* xpre = P.xpre4 + (size_t)l*N_NODES*D;
      float* bnpl = P.bnp + (size_t)l*(NBNP*40);

      for (int g = blockIdx.x; g < 12500; g += nblk) {
        const int node = g*4 + wv;
        const __bf16* rq = P.QS + (size_t)node*80 + half*40;

        float qf[20];
        {
          bf16x8 q0 = *(const bf16x8*)(rq);
          bf16x8 q1 = *(const bf16x8*)(rq + 8);
          bf16x4 q2 = *(const bf16x4*)(rq + 16);
#pragma unroll
          for (int i = 0; i < 8; i++) { qf[i] = (float)q0[i]; qf[8+i] = (float)q1[i]; }
#pragma unroll
          for (int i = 0; i < 4; i++) qf[16+i] = (float)q2[i];
        }

        const int beg = rowptr[node], end = rowptr[node+1];
        float z = 0.f;
        float S[20];
#pragma unroll
        for (int d = 0; d < 20; d++) S[d] = 0.f;

        for (int i = beg + sl; i < end; i += 32) {
          const int src = adj[i];
          const __bf16* kv = kvb + (size_t)src*64;   // one 128B line
          bf16x8 a0 = *(const bf16x8*)(kv);
          bf16x8 a1 = *(const bf16x8*)(kv + 8);
          bf16x8 a2 = *(const bf16x8*)(kv + 16);
          bf16x8 a3 = *(const bf16x8*)(kv + 24);
          bf16x8 a4 = *(const bf16x8*)(kv + 32);
          float d0 = 0.f;
#pragma unroll
          for (int j = 0; j < 8; j++) d0 += qf[j]     * (float)a0[j];
#pragma unroll
          for (int j = 0; j < 8; j++) d0 += qf[8 + j] * (float)a1[j];
#pragma unroll
          for (int j = 0; j < 4; j++) d0 += qf[16 + j]* (float)a2[j];
          const float w0 = __expf(fminf(d0*INV_SQRT_D, 80.f));
          z += w0;
#pragma unroll
          for (int d = 0; d < 4; d++) S[d]     += w0*(float)a2[4+d];
#pragma unroll
          for (int d = 0; d < 8; d++) S[4+d]   += w0*(float)a3[d];
#pragma unroll
          for (int d = 0; d < 8; d++) S[12+d]  += w0*(float)a4[d];
        }

#pragma unroll
        for (int o = 16; o >= 1; o >>= 1) {
          z += __shfl_xor(z, o, 64);
#pragma unroll
          for (int d = 0; d < 20; d++) S[d] += __shfl_xor(S[d], o, 64);
        }

        const float inv = (z > 0.f) ? 1.f/z : 0.f;
        float outv[20];
        {
          bf16x4 s0 = *(const bf16x4*)(rq + 20);
          bf16x8 s1 = *(const bf16x8*)(rq + 24);
          bf16x8 s2 = *(const bf16x8*)(rq + 32);
#pragma unroll
          for (int i2 = 0; i2 < 4; i2++) outv[i2] = S[i2]*inv + (float)s0[i2];
#pragma unroll
          for (int i2 = 0; i2 < 8; i2++) { outv[4+i2]  = S[4+i2]*inv  + (float)s1[i2];
                                           outv[12+i2] = S[12+i2]*inv + (float)s2[i2]; }
        }

        float x[20];
#pragma unroll
        for (int d = 0; d < 20; d++) {
          float o2 = __shfl_xor(outv[d], 32, 64);
          x[d] = cme*outv[d] + cot*o2;
        }

        if (lane == 0) {
          float* xo = xpre + (size_t)node*D;
#pragma unroll
          for (int j = 0; j < 5; j++) {
            float4 o4 = make_float4(x[4*j], x[4*j+1], x[4*j+2], x[4*j+3]);
            *(float4*)(xo + 4*j) = o4;
          }
        }

        float v = x[0];
#pragma unroll
        for (int d = 1; d < 20; d++) v = (sl == d) ? x[d] : v;
        if (sl < 20) {
          float* slot = bnpl + (size_t)(node & (NBNP-1))*40;
          if (half == 0) atomicAdd(&slot[sl], v);
          else           atomicAdd(&slot[20 + sl], v*v);
        }
      }
    }
    grid.sync();
  }

  // ============ final: BN+lrelu on 4 layers, concat @ Wout + bout ============
  {
    float* Ac   = (float*)smem;        // 80
    float* Bc   = (float*)smem + 80;   // 80
    float* wlds = (float*)smem + 160;  // 160
    __syncthreads();
    if (t < 80) {
      int l = t / 20, d = t % 20;
      const float* b = P.bnp + (size_t)l*(NBNP*40);
      float s1 = 0.f, s2 = 0.f;
      for (int s = 0; s < NBNP; s++) { s1 += b[s*40 + d]; s2 += b[s*40 + 20 + d]; }
      float mu  = s1 * (1.f/N_NODES);
      float var = s2 * (1.f/N_NODES) - mu*mu;
      float a = rsqrtf(var + 1e-5f) * P.gamma[t];
      Ac[t] = a; Bc[t] = P.beta[t] - mu*a;
    }
    if (t < 160) wlds[t] = P.Wout[t];
    __syncthreads();

    const float b0 = P.bout[0], b1 = P.bout[1];
    for (int tile = blockIdx.x; tile < 196; tile += nblk) {
      const int n = tile*256 + t;
      if (n >= N_NODES) continue;
      float a0 = b0, a1 = b1;
#pragma unroll
      for (int l = 0; l < 4; l++) {
        const float* base = P.xpre4 + (size_t)l*N_NODES*D + (size_t)n*D;
#pragma unroll
        for (int d = 0; d < D; d++) {
          int idx = l*20 + d;
          float y = base[d]*Ac[idx] + Bc[idx];
          y = (y > 0.f) ? y : 0.01f*y;
          a0 += y * wlds[idx*2 + 0];
          a1 += y * wlds[idx*2 + 1];
        }
      }
      P.out[n*2+0] = a0;
      P.out[n*2+1] = a1;
    }
  }
}

// ----------------------------------------------------------------------------------------
extern "C" void kernel_launch(void* const* d_in, const int* in_sizes, int n_in,
                              void* d_out, int out_size, void* d_ws, size_t ws_size,
                              hipStream_t stream)
{
  const float* feat = (const float*)d_in[0];
  const int*   same = (const int*)d_in[1];
  const int*   diff = (const int*)d_in[2];
  const float* W0q = (const float*)d_in[3];
  const float* b0q = (const float*)d_in[4];
  const float* W0k = (const float*)d_in[5];
  const float* b0k = (const float*)d_in[6];
  const float* W0v = (const float*)d_in[7];
  const float* b0v = (const float*)d_in[8];
  const float* W0s = (const float*)d_in[9];
  const float* b0s = (const float*)d_in[10];
  const float* Wq  = (const float*)d_in[11];
  const float* bq  = (const float*)d_in[12];
  const float* Wk  = (const float*)d_in[13];
  const float* bk  = (const float*)d_in[14];
  const float* Wv  = (const float*)d_in[15];
  const float* bv  = (const float*)d_in[16];
  const float* Ws_ = (const float*)d_in[17];
  const float* bs_ = (const float*)d_in[18];
  const float* w1  = (const float*)d_in[19];
  const float* w2  = (const float*)d_in[20];
  const float* gamma = (const float*)d_in[21];
  const float* beta  = (const float*)d_in[22];
  const float* Wout  = (const float*)d_in[23];
  const float* bout  = (const float*)d_in[24];

  float* wsf  = (float*)d_ws;
  __bf16*  QS    = (__bf16*)wsf;                 // 4,000,000 bf16 [N][80]
  __bf16*  KV0   = (__bf16*)(wsf + 2000000);     // 3,200,000 bf16 rows of 64 (128B)
  __bf16*  KV1   = (__bf16*)(wsf + 3600000);
  float*   XPRE4 = wsf + 5200000;                // 4,000,000  [4][N][20] pre-BN
  __bf16*  B0bf  = (__bf16*)(wsf + 9200000);     //   322,560 bf16
  float*   BIAS0 = wsf + 9361280;                //       160
  float*   WL    = wsf + 9361440;                //     9,600
  float*   BIASL = wsf + 9371040;                //       480
  float*   BNP   = wsf + 9371520;                //    10,240  [4][64][40]
  int*     ib    = (int*)(wsf + 9381760);
  int* DEG  = ib;                                // 100,000
  int* RP0  = ib + 100000;                       //  50,004
  int* RP1  = ib + 150004;                       //  50,004
  int* NX0  = ib + 200008;                       //  50,000
  int* NX1  = ib + 250008;                       //  50,000
  int* ADJ0 = ib + 300008;                       // 1,600,000
  int* ADJ1 = ib + 1900008;                      // 1,600,000

  const int packN = NCOL*KPAD + 160 + 9600 + 480 + 4*NBNP*40 + 2*N_NODES;  // 443,040
  pack_kernel<<<(packN + 255)/256, 256, 0, stream>>>(
      W0q, W0k, W0v, W0s, b0q, b0k, b0v, b0s,
      Wq, Wk, Wv, Ws_, bq, bk, bv, bs_,
      B0bf, BIAS0, WL, BIASL, BNP, DEG);

  const long nchunk = (2L*E_EDGES + SC_CHUNK - 1) / SC_CHUNK;
  hist_kernel<<<(int)(nchunk*8), 256, 0, stream>>>(same, diff, DEG);
  scan_kernel<<<2, 1024, 0, stream>>>(DEG, RP0, RP1, NX0, NX1);
  scatter_kernel<<<(int)(nchunk*8), 256, 0, stream>>>(same, diff, NX0, NX1, ADJ0, ADJ1);

  MegaP P;
  P.feat = feat; P.B0 = B0bf; P.bias0 = BIAS0;
  P.WL = WL; P.biasL = BIASL;
  P.w1 = w1; P.w2 = w2; P.gamma = gamma; P.beta = beta;
  P.Wout = Wout; P.bout = bout;
  P.rp0 = RP0; P.adj0 = ADJ0; P.rp1 = RP1; P.adj1 = ADJ1;
  P.QS = QS; P.KV0 = KV0; P.KV1 = KV1;
  P.xpre4 = XPRE4; P.bnp = BNP; P.out = (float*)d_out;

  int nb = 0;
  if (hipOccupancyMaxActiveBlocksPerMultiprocessor(&nb, (const void*)mega_kernel, 256, 0)
      != hipSuccess || nb < 1) nb = 2;
  if (nb > 8) nb = 8;
  int gridsz = nb * 256;   // co-resident by construction (256 CUs)

  void* kargs[] = { &P };
  hipLaunchCooperativeKernel((const void*)mega_kernel, dim3(gridsz), dim3(256),
                             kargs, 0, stream);
}